// Round 2
// baseline (562.383 us; speedup 1.0000x reference)
//
#include <hip/hip_runtime.h>
#include <hip/hip_bf16.h>
#include <cstdio>
#include <cstdint>

#define TNUM 2048
#define DDIM 768
#define HDIM 3072
#define ENUM 8

// counted vmcnt wait (keeps younger prefetch loads in flight across barriers)
#define WAITVM(N) asm volatile("s_waitcnt vmcnt(" #N ")" ::: "memory")
// compiler-level memory fence: stops LDS reads from being scheduled across a raw s_barrier
#define MEMFENCE() asm volatile("" ::: "memory")

typedef __attribute__((ext_vector_type(8))) __bf16 bf16x8;
typedef __attribute__((ext_vector_type(4))) float f32x4;
typedef __attribute__((ext_vector_type(8))) unsigned short ushort8_t;

__device__ __forceinline__ unsigned short f2bf(float f) {
    __bf16 h = (__bf16)f;            // RNE
    unsigned short u;
    __builtin_memcpy(&u, &h, 2);
    return u;
}

// async global->LDS, 16B per lane; LDS dest = wave-uniform base + lane*16
__device__ __forceinline__ void async_cp16(const unsigned short* g, unsigned short* l) {
    __builtin_amdgcn_global_load_lds((const __attribute__((address_space(1))) void*)g,
                                     (__attribute__((address_space(3))) void*)l,
                                     16, 0, 0);
}

// ---------------- cast x -> bf16 ----------------
__global__ void cast_x_kernel(const float* __restrict__ x, unsigned short* __restrict__ xb) {
    int i = (blockIdx.x * 256 + threadIdx.x) * 8;
    float4 a = *(const float4*)(x + i);
    float4 b = *(const float4*)(x + i + 4);
    ushort4 lo = make_ushort4(f2bf(a.x), f2bf(a.y), f2bf(a.z), f2bf(a.w));
    ushort4 hi = make_ushort4(f2bf(b.x), f2bf(b.y), f2bf(b.z), f2bf(b.w));
    *(ushort4*)(xb + i) = lo;
    *(ushort4*)(xb + i + 4) = hi;
}

// ---------------- transpose + cast weights to bf16 [n][k] ----------------
// 128x128 tiles. LDS tile word-granular; row pairing via shfl_xor(32); run-rotation
// swizzle keeps write conflicts at 4-way worst case; reads are ds_read_b128 + uniform rotate.
__global__ __launch_bounds__(256)
void transw_kernel(const float* __restrict__ W1, const float* __restrict__ W2,
                   const float* __restrict__ Ws1, const float* __restrict__ Ws2,
                   unsigned short* __restrict__ W1t, unsigned short* __restrict__ W2t,
                   unsigned short* __restrict__ Ws1t, unsigned short* __restrict__ Ws2t) {
    int z = blockIdx.z;
    const float* in; unsigned short* out; int R, C;
    if (z < 8)       { in = W1 + (size_t)z * DDIM * HDIM; out = W1t + (size_t)z * HDIM * DDIM; R = DDIM; C = HDIM; }
    else if (z < 16) { int e = z - 8; in = W2 + (size_t)e * HDIM * DDIM; out = W2t + (size_t)e * DDIM * HDIM; R = HDIM; C = DDIM; }
    else if (z == 16){ in = Ws1; out = Ws1t; R = DDIM; C = HDIM; }
    else             { in = Ws2; out = Ws2t; R = HDIM; C = DDIM; }
    int nx = C / 128;
    int c0 = (blockIdx.x % nx) * 128, r0 = (blockIdx.x / nx) * 128;
    __shared__ __align__(16) unsigned int tileT32[128 * 68];   // 34816 B
    int tid = threadIdx.x;
    int l15 = tid & 15;
    int g = tid >> 4;
    int par = (g >> 1) & 1;        // parity of this thread's input row
    int hf = g & 1;
    int cb = hf * 64 + l15 * 4;
    #pragma unroll
    for (int p = 0; p < 16; p++) {
        int unit = p * 16 + g;
        int r = unit >> 1;
        float4 v = *(const float4*)(in + (size_t)(r0 + r) * C + c0 + cb);
        unsigned int m01 = (unsigned int)f2bf(v.x) | ((unsigned int)f2bf(v.y) << 16);
        unsigned int m23 = (unsigned int)f2bf(v.z) | ((unsigned int)f2bf(v.w) << 16);
        unsigned int o01 = __shfl_xor(m01, 32);   // partner (lane^32) holds row r^1, same cols
        unsigned int o23 = __shfl_xor(m23, 32);
        unsigned int wA = par ? ((o23 & 0xffffu) | (m23 << 16))
                              : ((m01 & 0xffffu) | (o01 << 16));
        unsigned int wB = par ? ((o23 >> 16) | (m23 & 0xffff0000u))
                              : ((m01 >> 16) | (o01 & 0xffff0000u));
        int ca = cb + par * 2;
        int rp = unit >> 2;                       // pair index r>>1
        int cq = ca >> 2;                         // same for ca and ca+1
        int woff = 4 * (((rp >> 2) + 3 * cq) & 15) + (((rp & 3) + cq) & 3);
        tileT32[ca * 68 + woff] = wA;
        tileT32[(ca + 1) * 68 + woff] = wB;
    }
    __syncthreads();
    #pragma unroll
    for (int p = 0; p < 8; p++) {
        int cc = p * 16 + g;                      // output row (= input col)
        int cqp = cc >> 2;                        // wave-uniform
        const uint4 W = *(const uint4*)&tileT32[cc * 68 + 4 * ((l15 + 3 * cqp) & 15)];
        unsigned int a0 = W.x, a1 = W.y, a2 = W.z, a3 = W.w;
        int rsel = cqp & 3;                       // wave-uniform rotate to undo k-scramble
        if (rsel & 1) { unsigned int t = a0; a0 = a1; a1 = a2; a2 = a3; a3 = t; }
        if (rsel & 2) { unsigned int t0 = a0, t1 = a1; a0 = a2; a1 = a3; a2 = t0; a3 = t1; }
        uint4 ov; ov.x = a0; ov.y = a1; ov.z = a2; ov.w = a3;
        *(uint4*)(out + (size_t)(c0 + cc) * R + r0 + l15 * 8) = ov;   // rows l15*8..+8 in order
    }
}

// ---------------- router: one wave per token ----------------
__global__ void router_kernel(const float* __restrict__ x, const float* __restrict__ noise,
                              const float* __restrict__ Wr, const float* __restrict__ br,
                              int* __restrict__ counts, int* __restrict__ list,
                              int* __restrict__ inv, float* __restrict__ tokp) {
    int lane = threadIdx.x & 63;
    int t = blockIdx.x * 4 + (threadIdx.x >> 6);
    float acc[8];
    #pragma unroll
    for (int e = 0; e < 8; e++) acc[e] = 0.f;
    #pragma unroll
    for (int i = 0; i < 12; i++) {
        int d = i * 64 + lane;
        float xv = x[t * DDIM + d];
        float4 w0 = *(const float4*)(Wr + d * 8);
        float4 w1 = *(const float4*)(Wr + d * 8 + 4);
        acc[0] += xv * w0.x; acc[1] += xv * w0.y; acc[2] += xv * w0.z; acc[3] += xv * w0.w;
        acc[4] += xv * w1.x; acc[5] += xv * w1.y; acc[6] += xv * w1.z; acc[7] += xv * w1.w;
    }
    #pragma unroll
    for (int e = 0; e < 8; e++) {
        #pragma unroll
        for (int off2 = 32; off2 >= 1; off2 >>= 1)
            acc[e] += __shfl_xor(acc[e], off2, 64);
    }
    if (lane == 0) {
        float lg[8];
        #pragma unroll
        for (int e = 0; e < 8; e++) lg[e] = acc[e] + br[e] + 0.1f * noise[t * 8 + e];
        int e0 = 0;
        #pragma unroll
        for (int e = 1; e < 8; e++) if (lg[e] > lg[e0]) e0 = e;
        int e1 = -1;
        #pragma unroll
        for (int e = 0; e < 8; e++) if (e != e0 && (e1 < 0 || lg[e] > lg[e1])) e1 = e;
        float m = fmaxf(lg[e0], lg[e1]);
        float p0 = expf(lg[e0] - m), p1 = expf(lg[e1] - m);
        float inv_s = 1.f / (p0 + p1);
        int s0 = atomicAdd(&counts[e0], 1);
        list[e0 * TNUM + s0] = t;
        int s1 = atomicAdd(&counts[e1], 1);
        list[e1 * TNUM + s1] = t;
        inv[t * 2 + 0] = (e0 << 16) | s0;
        inv[t * 2 + 1] = (e1 << 16) | s1;
        tokp[t * 2 + 0] = p0 * inv_s;
        tokp[t * 2 + 1] = p1 * inv_s;
    }
}

// ---------------- prefix offsets + mixing scalars ----------------
__global__ void finalize_kernel(const int* __restrict__ counts, int* __restrict__ offs,
                                const float* __restrict__ alpha, const float* __restrict__ beta,
                                float* __restrict__ scal) {
    int s = 0;
    for (int e = 0; e < 8; e++) { offs[e] = s; s += counts[e]; }
    offs[8] = s;   // == 4096
    float a = alpha[0], b = beta[0];
    float m = fmaxf(a, b);
    float ea = expf(a - m), eb = expf(b - m);
    float inv = 1.f / (ea + eb);
    scal[0] = ea * inv;   // shared expert weight
    scal[1] = eb * inv;   // moe weight
}

// ================= FFN kernels =================
// Working-set discipline: grid (8, 48, 1); each block loops the 3 job-layers
// INTERNALLY (j = jz*8 + blockIdx.x). At any instant each XCD hosts ~1 job
// (A+B panels ~3MB < 4MB L2) instead of 3 jobs (~9-11MB, L2 thrash -> L3-BW
// bound ~4.4TB/s, which is what pinned both kernels at ~108us regardless of
// sync structure). Tile-replication traffic now hits L2.
// Pipeline: 3 LDS buffers, prefetch depth 2, raw s_barrier + counted vmcnt.
// Epilogue stores are nontemporal so write streams don't evict the job panels.

// ---------------- GEMM layer 1: h = leaky(x @ W1[e] + b1[e]) ----------------
// BM=128, BN=128, BK=32. 24 jobs:
//   j<16: expert e=j>>1, n-half nh=j&1 (A 0.75MB + B 2.25MB)
//   j>=16: shared slab ms=q>>1 (512 rows) x nh=q&1
__global__ __launch_bounds__(256, 3)
void ffn1_kernel(const unsigned short* __restrict__ xb,
                 const unsigned short* __restrict__ W1t,   // [8][3072][768]
                 const unsigned short* __restrict__ Ws1t,  // [3072][768]
                 const float* __restrict__ b1, const float* __restrict__ bs1,
                 const int* __restrict__ counts, const int* __restrict__ offs,
                 const int* __restrict__ list,
                 unsigned short* __restrict__ hbuf) {      // [6144][3072]
    __shared__ __align__(16) unsigned short As[3][512 * 8];   // 3 x 8KB
    __shared__ __align__(16) unsigned short Bs[3][512 * 8];   // 3 x 8KB  (48KB total)

    int y = blockIdx.y;                     // 0..47
    int mt0 = y / 12, ntl = y % 12;         // mt0 0..3, ntl 0..11
    int tid = threadIdx.x;
    int w = tid >> 6, lane = tid & 63;
    int l15 = lane & 15, quad = lane >> 4;
    int wm = (w & 1) * 64, wn = (w >> 1) * 64;
    int rcA = (w & 1) * 4;
    int rcB = (w >> 1) * 4;
    const int KT = DDIM / 32;   // 24

    int rowl[2], ldsoff[2];
    #pragma unroll
    for (int r = 0; r < 2; r++) {
        int rc = r * 4 + w;
        rowl[r] = rc * 16 + l15;
        ldsoff[r] = rc * 512;
    }

    for (int jz = 0; jz < 3; jz++) {
        int j = jz * 8 + blockIdx.x;        // 0..23
        int cnt, hbase, n0, mbase, ntiles;
        const unsigned short* Bmat;
        const float* bias;
        const int* lst = nullptr;
        if (j < 16) {
            int e = j >> 1, nh = j & 1;
            cnt = counts[e];
            ntiles = (cnt + 127) >> 7;
            mbase = 0;
            hbase = offs[e];
            n0 = nh * 1536 + ntl * 128;
            Bmat = W1t + (size_t)e * HDIM * DDIM;
            bias = b1 + e * HDIM;
            lst = list + e * TNUM;
        } else {
            int q = j - 16;                 // 0..7
            int ms = q >> 1, nh = q & 1;
            mbase = ms * 512;
            ntiles = 4;
            cnt = 1 << 30;
            hbase = 2 * TNUM;
            n0 = nh * 1536 + ntl * 128;
            Bmat = Ws1t;
            bias = bs1;
        }
        if (mt0 >= ntiles) continue;        // block-uniform

        const unsigned short* gB[2];
        #pragma unroll
        for (int r = 0; r < 2; r++)
            gB[r] = Bmat + (size_t)(n0 + rowl[r]) * DDIM + quad * 8;

        for (int mt = mt0; mt < ntiles; mt += 4) {
            int m0 = mbase + mt * 128;
            const unsigned short* gA[2];
            #pragma unroll
            for (int r = 0; r < 2; r++) {
                int row;
                if (lst) row = lst[min(m0 + rowl[r], cnt - 1)];
                else     row = m0 + rowl[r];
                gA[r] = xb + (size_t)row * DDIM + quad * 8;
            }

            f32x4 zero = {0.f, 0.f, 0.f, 0.f};
            f32x4 acc[4][4];
            #pragma unroll
            for (int i = 0; i < 4; i++)
                #pragma unroll
                for (int jj = 0; jj < 4; jj++) acc[i][jj] = zero;

            __builtin_amdgcn_s_barrier();       // prev iteration's LDS readers done
            MEMFENCE();
            // prologue: tiles 0 and 1
            #pragma unroll
            for (int t = 0; t < 2; t++)
                #pragma unroll
                for (int r = 0; r < 2; r++) {
                    async_cp16(gA[r] + t * 32, &As[t][ldsoff[r]]);
                    async_cp16(gB[r] + t * 32, &Bs[t][ldsoff[r]]);
                }

            #pragma unroll 1
            for (int kt = 0; kt < KT; kt++) {
                if (kt == KT - 1) { WAITVM(0); } else { WAITVM(4); }   // tile kt arrived; kt+1 in flight
                __builtin_amdgcn_s_barrier();
                MEMFENCE();
                int cur = kt % 3;
                if (kt + 2 < KT) {
                    int nb = (kt + 2) % 3;
                    int ko = (kt + 2) * 32;
                    #pragma unroll
                    for (int r = 0; r < 2; r++) {
                        async_cp16(gA[r] + ko, &As[nb][ldsoff[r]]);
                        async_cp16(gB[r] + ko, &Bs[nb][ldsoff[r]]);
                    }
                }
                bf16x8 af[4], bv[4];
                #pragma unroll
                for (int i = 0; i < 4; i++)
                    af[i] = *(const bf16x8*)&As[cur][((rcA + i) * 64 + quad * 16 + l15) * 8];
                #pragma unroll
                for (int jj = 0; jj < 4; jj++)
                    bv[jj] = *(const bf16x8*)&Bs[cur][((rcB + jj) * 64 + quad * 16 + l15) * 8];
                #pragma unroll
                for (int i = 0; i < 4; i++)
                    #pragma unroll
                    for (int jj = 0; jj < 4; jj++)
                        acc[i][jj] = __builtin_amdgcn_mfma_f32_16x16x32_bf16(af[i], bv[jj], acc[i][jj], 0, 0, 0);
            }

            #pragma unroll
            for (int i = 0; i < 4; i++) {
                int rbase = m0 + wm + i * 16 + quad * 4;
                #pragma unroll
                for (int jj = 0; jj < 4; jj++) {
                    int gc = n0 + wn + jj * 16 + l15;
                    float bvl = bias[gc];
                    #pragma unroll
                    for (int r = 0; r < 4; r++) {
                        int gr = rbase + r;
                        if (gr < cnt) {
                            float v = acc[i][jj][r] + bvl;
                            v = v > 0.f ? v : 0.01f * v;
                            __builtin_nontemporal_store(f2bf(v), &hbuf[(size_t)(hbase + gr) * HDIM + gc]);
                        }
                    }
                }
            }
        }
    }
}

// ---------------- GEMM layer 2: ybuf[kh] = h @ W2[e] (plain fp32 stores) ----------------
// BM=64, BN=128, BK=32, 3-buffer pipeline. 24 jobs:
//   j<16: expert e=j>>1, kh=j&1 (A 1.5MB + B-half 2.25MB)
//   j>=16: shared (mh 0..3, kh)
__global__ __launch_bounds__(256, 4)
void ffn2_kernel(const unsigned short* __restrict__ hbuf,
                 const unsigned short* __restrict__ W2t,   // [8][768][3072]
                 const unsigned short* __restrict__ Ws2t,  // [768][3072]
                 const int* __restrict__ counts, const int* __restrict__ offs,
                 float* __restrict__ ybuf) {               // [2][6144][768]
    __shared__ __align__(16) unsigned short As[3][256 * 8];   // 3 x 4KB
    __shared__ __align__(16) unsigned short Bs[3][512 * 8];   // 3 x 8KB (36KB total)

    int y = blockIdx.y;                     // 0..47
    int mt0 = y / 6, ntl = y % 6;           // mt0 0..7, ntl 0..5
    int n0 = ntl * 128;
    int tid = threadIdx.x;
    int w = tid >> 6, lane = tid & 63;
    int l15 = lane & 15, quad = lane >> 4;
    int wm = (w & 1) * 32, wn = (w >> 1) * 64;
    int rcA = (w & 1) * 2;
    int rcB = (w >> 1) * 4;
    const int KT = (HDIM / 2) / 32;   // 48
    int rowl = w * 16 + l15;

    for (int jz = 0; jz < 3; jz++) {
        int j = jz * 8 + blockIdx.x;        // 0..23
        int cnt, hbase, mbase, kh, ntiles;
        const unsigned short* Bmat;
        if (j < 16) {
            int e = j >> 1; kh = j & 1;
            cnt = counts[e];
            ntiles = (cnt + 63) >> 6;
            mbase = 0;
            hbase = offs[e];
            Bmat = W2t + (size_t)e * DDIM * HDIM;
        } else {
            int q = j - 16;
            int mh = q >> 1; kh = q & 1;
            mbase = mh * 512;
            ntiles = 8;
            cnt = 1 << 30;
            hbase = 2 * TNUM;
            Bmat = Ws2t;
        }
        if (mt0 >= ntiles) continue;        // block-uniform
        int kbase = kh * (HDIM / 2);

        const unsigned short* gB[2];
        int ldsoffB[2];
        #pragma unroll
        for (int r = 0; r < 2; r++) {
            int rc = r * 4 + w;
            gB[r] = Bmat + (size_t)(n0 + rc * 16 + l15) * HDIM + kbase + quad * 8;
            ldsoffB[r] = rc * 512;
        }
        float* yb = ybuf + (size_t)kh * 6144 * DDIM;

        for (int mt = mt0; mt < ntiles; mt += 8) {
            int m0 = mbase + mt * 64;
            int ra = (j < 16) ? min(m0 + rowl, cnt - 1) : (m0 + rowl);
            const unsigned short* gA0 = hbuf + (size_t)(hbase + ra) * HDIM + kbase + quad * 8;

            f32x4 zero = {0.f, 0.f, 0.f, 0.f};
            f32x4 acc[2][4];
            #pragma unroll
            for (int i = 0; i < 2; i++)
                #pragma unroll
                for (int jj = 0; jj < 4; jj++) acc[i][jj] = zero;

            __builtin_amdgcn_s_barrier();       // prev iteration's LDS readers done
            MEMFENCE();
            #pragma unroll
            for (int t = 0; t < 2; t++) {
                async_cp16(gA0 + t * 32, &As[t][w * 512]);
                #pragma unroll
                for (int r = 0; r < 2; r++) async_cp16(gB[r] + t * 32, &Bs[t][ldsoffB[r]]);
            }

            #pragma unroll 1
            for (int kt = 0; kt < KT; kt++) {
                if (kt == KT - 1) { WAITVM(0); } else { WAITVM(3); }
                __builtin_amdgcn_s_barrier();
                MEMFENCE();
                int cur = kt % 3;
                if (kt + 2 < KT) {
                    int nb = (kt + 2) % 3;
                    int ko = (kt + 2) * 32;
                    async_cp16(gA0 + ko, &As[nb][w * 512]);
                    #pragma unroll
                    for (int r = 0; r < 2; r++) async_cp16(gB[r] + ko, &Bs[nb][ldsoffB[r]]);
                }
                bf16x8 af[2], bv[4];
                #pragma unroll
                for (int i = 0; i < 2; i++)
                    af[i] = *(const bf16x8*)&As[cur][((rcA + i) * 64 + quad * 16 + l15) * 8];
                #pragma unroll
                for (int jj = 0; jj < 4; jj++)
                    bv[jj] = *(const bf16x8*)&Bs[cur][((rcB + jj) * 64 + quad * 16 + l15) * 8];
                #pragma unroll
                for (int i = 0; i < 2; i++)
                    #pragma unroll
                    for (int jj = 0; jj < 4; jj++)
                        acc[i][jj] = __builtin_amdgcn_mfma_f32_16x16x32_bf16(af[i], bv[jj], acc[i][jj], 0, 0, 0);
            }

            #pragma unroll
            for (int i = 0; i < 2; i++) {
                int rbase = m0 + wm + i * 16 + quad * 4;
                #pragma unroll
                for (int r = 0; r < 4; r++) {
                    int gr = rbase + r;
                    if (gr >= cnt) continue;
                    float* orow = yb + (size_t)(hbase + gr) * DDIM + n0 + wn;
                    #pragma unroll
                    for (int jj = 0; jj < 4; jj++)
                        __builtin_nontemporal_store(acc[i][jj][r], &orow[jj * 16 + l15]);
                }
            }
        }
    }
}

// ---------------- final mix: gather expert rows + shared, apply gates/biases ----------------
__global__ void mix_kernel(const float* __restrict__ ybuf, const int* __restrict__ inv,
                           const float* __restrict__ tokp, const int* __restrict__ offs,
                           const float* __restrict__ b2, const float* __restrict__ bs2,
                           const float* __restrict__ scal, float* __restrict__ out) {
    int t = blockIdx.x;
    int c = threadIdx.x * 4;          // blockDim = 192 -> covers 768
    int i0 = inv[t * 2 + 0], i1 = inv[t * 2 + 1];
    int e0 = i0 >> 16, sl0 = i0 & 0xFFFF;
    int e1 = i1 >> 16, sl1 = i1 & 0xFFFF;
    float p0 = tokp[t * 2 + 0], p1 = tokp[t * 2 + 1];
    float ws = scal[0], wmx = scal[1];
    size_t rA = (size_t)(offs[e0] + sl0) * DDIM + c;
    size_t rB = (size_t)(offs[e1] + sl1) * DDIM + c;
    size_t rS = (size_t)(2 * TNUM + t) * DDIM + c;
    const float* y0 = ybuf;
    const float* y1 = ybuf + (size_t)6144 * DDIM;
    float4 vA0 = *(const float4*)(y0 + rA);
    float4 vA1 = *(const float4*)(y1 + rA);
    float4 vB0 = *(const float4*)(y0 + rB);
    float4 vB1 = *(const float4*)(y1 + rB);
    float4 vS0 = *(const float4*)(y0 + rS);
    float4 vS1 = *(const float4*)(y1 + rS);
    float4 bA = *(const float4*)(b2 + e0 * DDIM + c);
    float4 bB = *(const float4*)(b2 + e1 * DDIM + c);
    float4 bS = *(const float4*)(bs2 + c);
    float4 o;
    o.x = ws * (vS0.x + vS1.x + bS.x) + wmx * (p0 * (vA0.x + vA1.x + bA.x) + p1 * (vB0.x + vB1.x + bB.x));
    o.y = ws * (vS0.y + vS1.y + bS.y) + wmx * (p0 * (vA0.y + vA1.y + bA.y) + p1 * (vB0.y + vB1.y + bB.y));
    o.z = ws * (vS0.z + vS1.z + bS.z) + wmx * (p0 * (vA0.z + vA1.z + bA.z) + p1 * (vB0.z + vB1.z + bB.z));
    o.w = ws * (vS0.w + vS1.w + bS.w) + wmx * (p0 * (vA0.w + vA1.w + bA.w) + p1 * (vB0.w + vB1.w + bB.w));
    *(float4*)(out + (size_t)t * DDIM + c) = o;
}

extern "C" void kernel_launch(void* const* d_in, const int* in_sizes, int n_in,
                              void* d_out, int out_size, void* d_ws, size_t ws_size,
                              hipStream_t stream) {
    const float* x     = (const float*)d_in[0];
    const float* noise = (const float*)d_in[1];
    const float* Wr    = (const float*)d_in[2];
    const float* br    = (const float*)d_in[3];
    const float* W1    = (const float*)d_in[4];
    const float* b1    = (const float*)d_in[5];
    const float* W2    = (const float*)d_in[6];
    const float* b2    = (const float*)d_in[7];
    const float* Ws1   = (const float*)d_in[8];
    const float* bs1   = (const float*)d_in[9];
    const float* Ws2   = (const float*)d_in[10];
    const float* bs2   = (const float*)d_in[11];
    const float* alpha = (const float*)d_in[12];
    const float* beta  = (const float*)d_in[13];

    char* ws = (char*)d_ws;
    size_t off = 0;
    auto alloc = [&](size_t bytes) -> char* {
        char* p = ws + off;
        off = (off + bytes + 255) & ~(size_t)255;
        return p;
    };
    int*   counts = (int*)  alloc(ENUM * 4);
    int*   offs   = (int*)  alloc(16 * 4);
    float* scal   = (float*)alloc(2 * 4);
    int*   list   = (int*)  alloc((size_t)ENUM * TNUM * 4);
    int*   inv    = (int*)  alloc((size_t)TNUM * 2 * 4);
    float* tokp   = (float*)alloc((size_t)TNUM * 2 * 4);
    unsigned short* xb   = (unsigned short*)alloc((size_t)TNUM * DDIM * 2);
    unsigned short* W1t  = (unsigned short*)alloc((size_t)ENUM * HDIM * DDIM * 2);  // 36 MB
    unsigned short* Ws1t = (unsigned short*)alloc((size_t)HDIM * DDIM * 2);         // 4.5 MB (adjacent)
    unsigned short* W2t  = (unsigned short*)alloc((size_t)ENUM * DDIM * HDIM * 2);
    unsigned short* Ws2t = (unsigned short*)alloc((size_t)DDIM * HDIM * 2);
    unsigned short* hbuf = (unsigned short*)alloc((size_t)(3 * TNUM) * HDIM * 2);
    // ybuf (2*6144*768*4 = 37.75 MB) aliases W1t+Ws1t (40.5 MB contiguous): last reader of
    // W1t/Ws1t is ffn1; ffn2 writes ybuf strictly after on the same stream.
    float* ybuf = (float*)W1t;
    if (off > ws_size) {
        fprintf(stderr, "kernel_launch: workspace too small (need %zu, have %zu)\n", off, ws_size);
        return;
    }

    hipMemsetAsync(counts, 0, ENUM * 4, stream);

    cast_x_kernel<<<dim3((TNUM * DDIM / 8) / 256), dim3(256), 0, stream>>>(x, xb);
    transw_kernel<<<dim3(144, 1, 18), dim3(256), 0, stream>>>(W1, W2, Ws1, Ws2, W1t, W2t, Ws1t, Ws2t);
    router_kernel<<<dim3(TNUM / 4), dim3(256), 0, stream>>>(x, noise, Wr, br, counts, list, inv, tokp);
    finalize_kernel<<<dim3(1), dim3(1), 0, stream>>>(counts, offs, alpha, beta, scal);
    // persistent z-loop grids: x = 8 (XCD slot), y = 48 tiles; 3 jobs iterated in-kernel
    ffn1_kernel<<<dim3(8, 48, 1), dim3(256), 0, stream>>>(xb, W1t, Ws1t, b1, bs1, counts, offs, list, hbuf);
    ffn2_kernel<<<dim3(8, 48, 1), dim3(256), 0, stream>>>(hbuf, W2t, Ws2t, counts, offs, ybuf);
    mix_kernel<<<dim3(TNUM), dim3(192), 0, stream>>>(ybuf, inv, tokp, offs, b2, bs2, scal, (float*)d_out);
}

// Round 3
// 506.678 us; speedup vs baseline: 1.1099x; 1.1099x over previous
//
#include <hip/hip_runtime.h>
#include <hip/hip_bf16.h>
#include <cstdio>
#include <cstdint>

#define TNUM 2048
#define DDIM 768
#define HDIM 3072
#define ENUM 8

// counted vmcnt wait (keeps younger prefetch loads in flight across barriers)
#define WAITVM(N) asm volatile("s_waitcnt vmcnt(" #N ")" ::: "memory")
// compiler-level memory fence: stops LDS reads from being scheduled across a raw s_barrier
#define MEMFENCE() asm volatile("" ::: "memory")

typedef __attribute__((ext_vector_type(8))) __bf16 bf16x8;
typedef __attribute__((ext_vector_type(4))) float f32x4;

__device__ __forceinline__ unsigned short f2bf(float f) {
    __bf16 h = (__bf16)f;            // RNE
    unsigned short u;
    __builtin_memcpy(&u, &h, 2);
    return u;
}

// async global->LDS, 16B per lane; LDS dest = wave-uniform base + lane*16
__device__ __forceinline__ void async_cp16(const unsigned short* g, unsigned short* l) {
    __builtin_amdgcn_global_load_lds((const __attribute__((address_space(1))) void*)g,
                                     (__attribute__((address_space(3))) void*)l,
                                     16, 0, 0);
}

// ---------------- 128x128 transpose+cast tile (device fn, shared by both hetero hosts) ----
// LDS word-granular; row-pairing via shfl_xor(32); run-rotation swizzle -> <=4-way write
// conflicts; reads ds_read_b128 + wave-uniform rotate. Needs 34816 B of LDS.
__device__ __forceinline__ void transpose_tile(const float* __restrict__ in,
                                               unsigned short* __restrict__ out,
                                               int R, int C, int c0, int r0,
                                               unsigned int* tileT32) {
    int tid = threadIdx.x;
    int l15 = tid & 15;
    int g = tid >> 4;
    int par = (g >> 1) & 1;        // parity of this thread's input row
    int hf = g & 1;
    int cb = hf * 64 + l15 * 4;
    #pragma unroll
    for (int p = 0; p < 16; p++) {
        int unit = p * 16 + g;
        int r = unit >> 1;
        float4 v = *(const float4*)(in + (size_t)(r0 + r) * C + c0 + cb);
        unsigned int m01 = (unsigned int)f2bf(v.x) | ((unsigned int)f2bf(v.y) << 16);
        unsigned int m23 = (unsigned int)f2bf(v.z) | ((unsigned int)f2bf(v.w) << 16);
        unsigned int o01 = __shfl_xor(m01, 32);   // partner (lane^32) holds row r^1, same cols
        unsigned int o23 = __shfl_xor(m23, 32);
        unsigned int wA = par ? ((o23 & 0xffffu) | (m23 << 16))
                              : ((m01 & 0xffffu) | (o01 << 16));
        unsigned int wB = par ? ((o23 >> 16) | (m23 & 0xffff0000u))
                              : ((m01 >> 16) | (o01 & 0xffff0000u));
        int ca = cb + par * 2;
        int rp = unit >> 2;                       // pair index r>>1
        int cq = ca >> 2;                         // same for ca and ca+1
        int woff = 4 * (((rp >> 2) + 3 * cq) & 15) + (((rp & 3) + cq) & 3);
        tileT32[ca * 68 + woff] = wA;
        tileT32[(ca + 1) * 68 + woff] = wB;
    }
    __syncthreads();
    #pragma unroll
    for (int p = 0; p < 8; p++) {
        int cc = p * 16 + g;                      // output row (= input col)
        int cqp = cc >> 2;                        // wave-uniform
        const uint4 W = *(const uint4*)&tileT32[cc * 68 + 4 * ((l15 + 3 * cqp) & 15)];
        unsigned int a0 = W.x, a1 = W.y, a2 = W.z, a3 = W.w;
        int rsel = cqp & 3;                       // wave-uniform rotate to undo k-scramble
        if (rsel & 1) { unsigned int t = a0; a0 = a1; a1 = a2; a2 = a3; a3 = t; }
        if (rsel & 2) { unsigned int t0 = a0, t1 = a1; a0 = a2; a1 = a3; a2 = t0; a3 = t1; }
        uint4 ov; ov.x = a0; ov.y = a1; ov.z = a2; ov.w = a3;
        *(uint4*)(out + (size_t)(c0 + cc) * R + r0 + l15 * 8) = ov;   // rows l15*8..+8 in order
    }
}

// ---------------- kernel 1: transw(W1,Ws1) || cast_x || router ----------------
// blocks [0,1296): transpose W1[e]/Ws1 (all are 768x3072 -> [3072][768])
// blocks [1296,2064): cast x -> bf16
// blocks [2064,2576): router (one wave per token)
__global__ __launch_bounds__(256)
void pre_kernel(const float* __restrict__ x, const float* __restrict__ noise,
                const float* __restrict__ Wr, const float* __restrict__ br,
                const float* __restrict__ W1, const float* __restrict__ Ws1,
                unsigned short* __restrict__ W1t, unsigned short* __restrict__ Ws1t,
                unsigned short* __restrict__ xb,
                int* __restrict__ counts, int* __restrict__ list,
                int* __restrict__ inv, float* __restrict__ tokp) {
    __shared__ __align__(16) unsigned int tileT32[128 * 68];   // 34816 B
    int b = blockIdx.x;
    if (b < 1296) {
        int m = b / 144, t = b % 144;   // 9 matrices (W1[0..7], Ws1), 24x6=144 tiles each
        const float* in       = (m < 8) ? (W1 + (size_t)m * DDIM * HDIM) : Ws1;
        unsigned short* out   = (m < 8) ? (W1t + (size_t)m * HDIM * DDIM) : Ws1t;
        // R=768 rows, C=3072 cols, nx=24
        transpose_tile(in, out, DDIM, HDIM, (t % 24) * 128, (t / 24) * 128, tileT32);
        return;
    }
    if (b < 2064) {
        int i = ((b - 1296) * 256 + threadIdx.x) * 8;
        float4 a = *(const float4*)(x + i);
        float4 bb = *(const float4*)(x + i + 4);
        ushort4 lo = make_ushort4(f2bf(a.x), f2bf(a.y), f2bf(a.z), f2bf(a.w));
        ushort4 hi = make_ushort4(f2bf(bb.x), f2bf(bb.y), f2bf(bb.z), f2bf(bb.w));
        *(ushort4*)(xb + i) = lo;
        *(ushort4*)(xb + i + 4) = hi;
        return;
    }
    // ---- router ----
    int lane = threadIdx.x & 63;
    int t = (b - 2064) * 4 + (threadIdx.x >> 6);
    float acc[8];
    #pragma unroll
    for (int e = 0; e < 8; e++) acc[e] = 0.f;
    #pragma unroll
    for (int i = 0; i < 12; i++) {
        int d = i * 64 + lane;
        float xv = x[t * DDIM + d];
        float4 w0 = *(const float4*)(Wr + d * 8);
        float4 w1 = *(const float4*)(Wr + d * 8 + 4);
        acc[0] += xv * w0.x; acc[1] += xv * w0.y; acc[2] += xv * w0.z; acc[3] += xv * w0.w;
        acc[4] += xv * w1.x; acc[5] += xv * w1.y; acc[6] += xv * w1.z; acc[7] += xv * w1.w;
    }
    #pragma unroll
    for (int e = 0; e < 8; e++) {
        #pragma unroll
        for (int off2 = 32; off2 >= 1; off2 >>= 1)
            acc[e] += __shfl_xor(acc[e], off2, 64);
    }
    if (lane == 0) {
        float lg[8];
        #pragma unroll
        for (int e = 0; e < 8; e++) lg[e] = acc[e] + br[e] + 0.1f * noise[t * 8 + e];
        int e0 = 0;
        #pragma unroll
        for (int e = 1; e < 8; e++) if (lg[e] > lg[e0]) e0 = e;
        int e1 = -1;
        #pragma unroll
        for (int e = 0; e < 8; e++) if (e != e0 && (e1 < 0 || lg[e] > lg[e1])) e1 = e;
        float m = fmaxf(lg[e0], lg[e1]);
        float p0 = expf(lg[e0] - m), p1 = expf(lg[e1] - m);
        float inv_s = 1.f / (p0 + p1);
        int s0 = atomicAdd(&counts[e0], 1);
        list[e0 * TNUM + s0] = t;
        int s1 = atomicAdd(&counts[e1], 1);
        list[e1 * TNUM + s1] = t;
        inv[t * 2 + 0] = (e0 << 16) | s0;
        inv[t * 2 + 1] = (e1 << 16) | s1;
        tokp[t * 2 + 0] = p0 * inv_s;
        tokp[t * 2 + 1] = p1 * inv_s;
    }
}

// ---------------- kernel 2: ffn1 (R1 structure, z=0..2) || transw(W2,Ws2) (z=3..6) ------
// ffn1: BM=128, BN=128, BK=32, 3 LDS buffers, depth-2 prefetch, counted vmcnt.
// 24 jobs: j<16 expert e=j>>1, n-half nh=j&1; j>=16 shared slab (512 rows) x nh.
// transw2: 9 matrices (W2[0..7], Ws2), all 3072x768 -> [768][3072], 144 tiles each.
__global__ __launch_bounds__(256, 3)
void ffn1_kernel(const unsigned short* __restrict__ xb,
                 const unsigned short* __restrict__ W1t,   // [8][3072][768]
                 const unsigned short* __restrict__ Ws1t,  // [3072][768]
                 const float* __restrict__ b1, const float* __restrict__ bs1,
                 const int* __restrict__ counts, const int* __restrict__ list,
                 unsigned short* __restrict__ hbuf,        // [6144][3072]
                 const float* __restrict__ W2, const float* __restrict__ Ws2,
                 unsigned short* __restrict__ W2t, unsigned short* __restrict__ Ws2t) {
    __shared__ __align__(16) unsigned char smem[49152];

    if (blockIdx.z >= 3) {
        int q = (blockIdx.z - 3) * 384 + blockIdx.y * 8 + blockIdx.x;
        if (q >= 1296) return;
        int m = q / 144, t = q % 144;   // R=3072 rows, C=768 cols, nx=6
        const float* in     = (m < 8) ? (W2 + (size_t)m * HDIM * DDIM) : Ws2;
        unsigned short* out = (m < 8) ? (W2t + (size_t)m * DDIM * HDIM) : Ws2t;
        transpose_tile(in, out, HDIM, DDIM, (t % 6) * 128, (t / 6) * 128, (unsigned int*)smem);
        return;
    }

    unsigned short* As = (unsigned short*)smem;            // [3][4096]
    unsigned short* Bs = (unsigned short*)(smem + 24576);  // [3][4096]

    int j = blockIdx.z * 8 + blockIdx.x;    // 0..23
    int y = blockIdx.y;                     // 0..47
    int mt0 = y / 12, ntl = y % 12;         // mt0 0..3, ntl 0..11

    int offv[8];
    { int s = 0;
      #pragma unroll
      for (int e = 0; e < 8; e++) { offv[e] = s; s += counts[e]; } }

    int cnt, hbase, n0, mbase, ntiles;
    const unsigned short* Bmat;
    const float* bias;
    const int* lst = nullptr;
    if (j < 16) {
        int e = j >> 1, nh = j & 1;
        cnt = counts[e];
        ntiles = (cnt + 127) >> 7;
        mbase = 0;
        hbase = offv[e];
        n0 = nh * 1536 + ntl * 128;
        Bmat = W1t + (size_t)e * HDIM * DDIM;
        bias = b1 + e * HDIM;
        lst = list + e * TNUM;
    } else {
        int q = j - 16;                     // 0..7
        int ms = q >> 1, nh = q & 1;
        mbase = ms * 512;
        ntiles = 4;
        cnt = 1 << 30;
        hbase = 2 * TNUM;
        n0 = nh * 1536 + ntl * 128;
        Bmat = Ws1t;
        bias = bs1;
    }
    if (mt0 >= ntiles) return;

    int tid = threadIdx.x;
    int w = tid >> 6, lane = tid & 63;
    int l15 = lane & 15, quad = lane >> 4;
    int wm = (w & 1) * 64, wn = (w >> 1) * 64;
    int rcA = (w & 1) * 4;
    int rcB = (w >> 1) * 4;
    const int KT = DDIM / 32;   // 24

    const unsigned short* gB[2];
    int ldsoff[2], rowl[2];
    #pragma unroll
    for (int r = 0; r < 2; r++) {
        int rc = r * 4 + w;
        rowl[r] = rc * 16 + l15;
        ldsoff[r] = rc * 512;
        gB[r] = Bmat + (size_t)(n0 + rowl[r]) * DDIM + quad * 8;
    }

    for (int mt = mt0; mt < ntiles; mt += 4) {
        int m0 = mbase + mt * 128;
        const unsigned short* gA[2];
        #pragma unroll
        for (int r = 0; r < 2; r++) {
            int row;
            if (lst) row = lst[min(m0 + rowl[r], cnt - 1)];
            else     row = m0 + rowl[r];
            gA[r] = xb + (size_t)row * DDIM + quad * 8;
        }

        f32x4 zero = {0.f, 0.f, 0.f, 0.f};
        f32x4 acc[4][4];
        #pragma unroll
        for (int i = 0; i < 4; i++)
            #pragma unroll
            for (int jj = 0; jj < 4; jj++) acc[i][jj] = zero;

        __builtin_amdgcn_s_barrier();       // prev iteration's LDS readers done
        MEMFENCE();
        #pragma unroll
        for (int t = 0; t < 2; t++)
            #pragma unroll
            for (int r = 0; r < 2; r++) {
                async_cp16(gA[r] + t * 32, As + t * 4096 + ldsoff[r]);
                async_cp16(gB[r] + t * 32, Bs + t * 4096 + ldsoff[r]);
            }

        #pragma unroll 1
        for (int kt = 0; kt < KT; kt++) {
            if (kt == KT - 1) { WAITVM(0); } else { WAITVM(4); }   // tile kt arrived; kt+1 in flight
            __builtin_amdgcn_s_barrier();
            MEMFENCE();
            int cur = kt % 3;
            if (kt + 2 < KT) {
                int nb = (kt + 2) % 3;
                int ko = (kt + 2) * 32;
                #pragma unroll
                for (int r = 0; r < 2; r++) {
                    async_cp16(gA[r] + ko, As + nb * 4096 + ldsoff[r]);
                    async_cp16(gB[r] + ko, Bs + nb * 4096 + ldsoff[r]);
                }
            }
            bf16x8 af[4], bv[4];
            #pragma unroll
            for (int i = 0; i < 4; i++)
                af[i] = *(const bf16x8*)(As + cur * 4096 + ((rcA + i) * 64 + quad * 16 + l15) * 8);
            #pragma unroll
            for (int jj = 0; jj < 4; jj++)
                bv[jj] = *(const bf16x8*)(Bs + cur * 4096 + ((rcB + jj) * 64 + quad * 16 + l15) * 8);
            #pragma unroll
            for (int i = 0; i < 4; i++)
                #pragma unroll
                for (int jj = 0; jj < 4; jj++)
                    acc[i][jj] = __builtin_amdgcn_mfma_f32_16x16x32_bf16(af[i], bv[jj], acc[i][jj], 0, 0, 0);
        }

        #pragma unroll
        for (int i = 0; i < 4; i++) {
            int rbase = m0 + wm + i * 16 + quad * 4;
            #pragma unroll
            for (int jj = 0; jj < 4; jj++) {
                int gc = n0 + wn + jj * 16 + l15;
                float bvl = bias[gc];
                #pragma unroll
                for (int r = 0; r < 4; r++) {
                    int gr = rbase + r;
                    if (gr < cnt) {
                        float v = acc[i][jj][r] + bvl;
                        v = v > 0.f ? v : 0.01f * v;
                        hbuf[(size_t)(hbase + gr) * HDIM + gc] = f2bf(v);
                    }
                }
            }
        }
    }
}

// ---------------- kernel 3: ffn2 full-K: ybuf = h @ W2[e] (single fp32 buffer) --------
// BM=64, BN=128, BK=32, KT=96 (full K=3072), 3 LDS buffers, depth-2, counted vmcnt.
// 16 jobs: j<8 expert e=j; j>=8 shared slab (j-8)*256 rows (ntiles=4).
__global__ __launch_bounds__(256, 4)
void ffn2_kernel(const unsigned short* __restrict__ hbuf,
                 const unsigned short* __restrict__ W2t,   // [8][768][3072]
                 const unsigned short* __restrict__ Ws2t,  // [768][3072]
                 const int* __restrict__ counts,
                 float* __restrict__ ybuf) {               // [6144][768]
    __shared__ __align__(16) unsigned short As[3][256 * 8];   // 3 x 4KB
    __shared__ __align__(16) unsigned short Bs[3][512 * 8];   // 3 x 8KB (36KB total)

    int j = blockIdx.z * 8 + blockIdx.x;    // 0..15
    int y = blockIdx.y;                     // 0..47
    int mt0 = y / 6, ntl = y % 6;           // mt0 0..7, ntl 0..5
    int n0 = ntl * 128;

    int offv[8];
    { int s = 0;
      #pragma unroll
      for (int e = 0; e < 8; e++) { offv[e] = s; s += counts[e]; } }

    int cnt, hbase, mbase, ntiles;
    const unsigned short* Bmat;
    if (j < 8) {
        int e = j;
        cnt = counts[e];
        ntiles = (cnt + 63) >> 6;
        mbase = 0;
        hbase = offv[e];
        Bmat = W2t + (size_t)e * DDIM * HDIM;
    } else {
        int s = j - 8;                      // 0..7, 256 rows each
        mbase = s * 256;
        ntiles = 4;
        cnt = 1 << 30;
        hbase = 2 * TNUM;
        Bmat = Ws2t;
    }
    if (mt0 >= ntiles) return;

    int tid = threadIdx.x;
    int w = tid >> 6, lane = tid & 63;
    int l15 = lane & 15, quad = lane >> 4;
    int wm = (w & 1) * 32, wn = (w >> 1) * 64;
    int rcA = (w & 1) * 2;
    int rcB = (w >> 1) * 4;
    const int KT = HDIM / 32;   // 96
    int rowl = w * 16 + l15;

    const unsigned short* gB[2];
    int ldsoffB[2];
    #pragma unroll
    for (int r = 0; r < 2; r++) {
        int rc = r * 4 + w;
        gB[r] = Bmat + (size_t)(n0 + rc * 16 + l15) * HDIM + quad * 8;
        ldsoffB[r] = rc * 512;
    }

    for (int mt = mt0; mt < ntiles; mt += 8) {
        int m0 = mbase + mt * 64;
        int ra = (j < 8) ? min(m0 + rowl, cnt - 1) : (m0 + rowl);
        const unsigned short* gA0 = hbuf + (size_t)(hbase + ra) * HDIM + quad * 8;

        f32x4 zero = {0.f, 0.f, 0.f, 0.f};
        f32x4 acc[2][4];
        #pragma unroll
        for (int i = 0; i < 2; i++)
            #pragma unroll
            for (int jj = 0; jj < 4; jj++) acc[i][jj] = zero;

        __builtin_amdgcn_s_barrier();       // prev iteration's LDS readers done
        MEMFENCE();
        #pragma unroll
        for (int t = 0; t < 2; t++) {
            async_cp16(gA0 + t * 32, &As[t][w * 512]);
            #pragma unroll
            for (int r = 0; r < 2; r++) async_cp16(gB[r] + t * 32, &Bs[t][ldsoffB[r]]);
        }

        #pragma unroll 1
        for (int kt = 0; kt < KT; kt++) {
            if (kt == KT - 1) { WAITVM(0); } else { WAITVM(3); }
            __builtin_amdgcn_s_barrier();
            MEMFENCE();
            int cur = kt % 3;
            if (kt + 2 < KT) {
                int nb = (kt + 2) % 3;
                int ko = (kt + 2) * 32;
                async_cp16(gA0 + ko, &As[nb][w * 512]);
                #pragma unroll
                for (int r = 0; r < 2; r++) async_cp16(gB[r] + ko, &Bs[nb][ldsoffB[r]]);
            }
            bf16x8 af[2], bv[4];
            #pragma unroll
            for (int i = 0; i < 2; i++)
                af[i] = *(const bf16x8*)&As[cur][((rcA + i) * 64 + quad * 16 + l15) * 8];
            #pragma unroll
            for (int jj = 0; jj < 4; jj++)
                bv[jj] = *(const bf16x8*)&Bs[cur][((rcB + jj) * 64 + quad * 16 + l15) * 8];
            #pragma unroll
            for (int i = 0; i < 2; i++)
                #pragma unroll
                for (int jj = 0; jj < 4; jj++)
                    acc[i][jj] = __builtin_amdgcn_mfma_f32_16x16x32_bf16(af[i], bv[jj], acc[i][jj], 0, 0, 0);
        }

        #pragma unroll
        for (int i = 0; i < 2; i++) {
            int rbase = m0 + wm + i * 16 + quad * 4;
            #pragma unroll
            for (int r = 0; r < 4; r++) {
                int gr = rbase + r;
                if (gr >= cnt) continue;
                float* orow = ybuf + (size_t)(hbase + gr) * DDIM + n0 + wn;
                #pragma unroll
                for (int jj = 0; jj < 4; jj++)
                    orow[jj * 16 + l15] = acc[i][jj][r];
            }
        }
    }
}

// ---------------- kernel 4: final mix (offs + softmax(alpha,beta) inline) ----------------
__global__ void mix_kernel(const float* __restrict__ ybuf, const int* __restrict__ inv,
                           const float* __restrict__ tokp, const int* __restrict__ counts,
                           const float* __restrict__ b2, const float* __restrict__ bs2,
                           const float* __restrict__ alpha, const float* __restrict__ beta,
                           float* __restrict__ out) {
    int t = blockIdx.x;
    int c = threadIdx.x * 4;          // blockDim = 192 -> covers 768
    int offv[8];
    { int s = 0;
      #pragma unroll
      for (int e = 0; e < 8; e++) { offv[e] = s; s += counts[e]; } }
    float a = alpha[0], bsc = beta[0];
    float m = fmaxf(a, bsc);
    float ea = expf(a - m), eb = expf(bsc - m);
    float is = 1.f / (ea + eb);
    float ws = ea * is, wmx = eb * is;

    int i0 = inv[t * 2 + 0], i1 = inv[t * 2 + 1];
    int e0 = i0 >> 16, sl0 = i0 & 0xFFFF;
    int e1 = i1 >> 16, sl1 = i1 & 0xFFFF;
    float p0 = tokp[t * 2 + 0], p1 = tokp[t * 2 + 1];
    size_t rA = (size_t)(offv[e0] + sl0) * DDIM + c;
    size_t rB = (size_t)(offv[e1] + sl1) * DDIM + c;
    size_t rS = (size_t)(2 * TNUM + t) * DDIM + c;
    float4 vA = *(const float4*)(ybuf + rA);
    float4 vB = *(const float4*)(ybuf + rB);
    float4 vS = *(const float4*)(ybuf + rS);
    float4 bA = *(const float4*)(b2 + e0 * DDIM + c);
    float4 bB = *(const float4*)(b2 + e1 * DDIM + c);
    float4 bS = *(const float4*)(bs2 + c);
    float4 o;
    o.x = ws * (vS.x + bS.x) + wmx * (p0 * (vA.x + bA.x) + p1 * (vB.x + bB.x));
    o.y = ws * (vS.y + bS.y) + wmx * (p0 * (vA.y + bA.y) + p1 * (vB.y + bB.y));
    o.z = ws * (vS.z + bS.z) + wmx * (p0 * (vA.z + bA.z) + p1 * (vB.z + bB.z));
    o.w = ws * (vS.w + bS.w) + wmx * (p0 * (vA.w + bA.w) + p1 * (vB.w + bB.w));
    *(float4*)(out + (size_t)t * DDIM + c) = o;
}

extern "C" void kernel_launch(void* const* d_in, const int* in_sizes, int n_in,
                              void* d_out, int out_size, void* d_ws, size_t ws_size,
                              hipStream_t stream) {
    const float* x     = (const float*)d_in[0];
    const float* noise = (const float*)d_in[1];
    const float* Wr    = (const float*)d_in[2];
    const float* br    = (const float*)d_in[3];
    const float* W1    = (const float*)d_in[4];
    const float* b1    = (const float*)d_in[5];
    const float* W2    = (const float*)d_in[6];
    const float* b2    = (const float*)d_in[7];
    const float* Ws1   = (const float*)d_in[8];
    const float* bs1   = (const float*)d_in[9];
    const float* Ws2   = (const float*)d_in[10];
    const float* bs2   = (const float*)d_in[11];
    const float* alpha = (const float*)d_in[12];
    const float* beta  = (const float*)d_in[13];

    char* ws = (char*)d_ws;
    size_t off = 0;
    auto alloc = [&](size_t bytes) -> char* {
        char* p = ws + off;
        off = (off + bytes + 255) & ~(size_t)255;
        return p;
    };
    int*   counts = (int*)  alloc(ENUM * 4);
    int*   list   = (int*)  alloc((size_t)ENUM * TNUM * 4);
    int*   inv    = (int*)  alloc((size_t)TNUM * 2 * 4);
    float* tokp   = (float*)alloc((size_t)TNUM * 2 * 4);
    unsigned short* xb   = (unsigned short*)alloc((size_t)TNUM * DDIM * 2);
    unsigned short* W1t  = (unsigned short*)alloc((size_t)ENUM * HDIM * DDIM * 2);  // 36 MB
    unsigned short* Ws1t = (unsigned short*)alloc((size_t)HDIM * DDIM * 2);         // 4.5 MB (adjacent)
    unsigned short* W2t  = (unsigned short*)alloc((size_t)ENUM * DDIM * HDIM * 2);
    unsigned short* Ws2t = (unsigned short*)alloc((size_t)DDIM * HDIM * 2);
    unsigned short* hbuf = (unsigned short*)alloc((size_t)(3 * TNUM) * HDIM * 2);
    // ybuf (6144*768*4 = 18.9 MB) aliases W1t (36 MB): last reader of W1t is ffn1 (k2);
    // ffn2 writes ybuf strictly after on the same stream.
    float* ybuf = (float*)W1t;
    if (off > ws_size) {
        fprintf(stderr, "kernel_launch: workspace too small (need %zu, have %zu)\n", off, ws_size);
        return;
    }

    hipMemsetAsync(counts, 0, ENUM * 4, stream);

    // k1: transw(W1,Ws1) || cast_x || router  (1296 + 768 + 512 blocks)
    pre_kernel<<<dim3(2576), dim3(256), 0, stream>>>(x, noise, Wr, br, W1, Ws1,
                                                     W1t, Ws1t, xb, counts, list, inv, tokp);
    // k2: ffn1 (z=0..2) || transw(W2,Ws2) (z=3..6)
    ffn1_kernel<<<dim3(8, 48, 7), dim3(256), 0, stream>>>(xb, W1t, Ws1t, b1, bs1, counts, list,
                                                          hbuf, W2, Ws2, W2t, Ws2t);
    // k3: ffn2 full-K, 16 jobs
    ffn2_kernel<<<dim3(8, 48, 2), dim3(256), 0, stream>>>(hbuf, W2t, Ws2t, counts, ybuf);
    // k4: mix
    mix_kernel<<<dim3(TNUM), dim3(192), 0, stream>>>(ybuf, inv, tokp, counts, b2, bs2,
                                                     alpha, beta, (float*)d_out);
}

// Round 4
// 443.605 us; speedup vs baseline: 1.2678x; 1.1422x over previous
//
#include <hip/hip_runtime.h>
#include <hip/hip_bf16.h>
#include <cstdio>
#include <cstdint>

#define TNUM 2048
#define DDIM 768
#define HDIM 3072
#define ENUM 8

// counted vmcnt wait (keeps younger prefetch loads in flight across barriers)
#define WAITVM(N) asm volatile("s_waitcnt vmcnt(" #N ")" ::: "memory")
// compiler-level memory fence: stops LDS reads from being scheduled across a raw s_barrier
#define MEMFENCE() asm volatile("" ::: "memory")

typedef __attribute__((ext_vector_type(8))) __bf16 bf16x8;
typedef __attribute__((ext_vector_type(4))) float f32x4;

__device__ __forceinline__ unsigned short f2bf(float f) {
    __bf16 h = (__bf16)f;            // RNE
    unsigned short u;
    __builtin_memcpy(&u, &h, 2);
    return u;
}

// async global->LDS, 16B per lane; LDS dest = wave-uniform base + lane*16
__device__ __forceinline__ void async_cp16(const unsigned short* g, unsigned short* l) {
    __builtin_amdgcn_global_load_lds((const __attribute__((address_space(1))) void*)g,
                                     (__attribute__((address_space(3))) void*)l,
                                     16, 0, 0);
}

// ---------------- 128x128 transpose+cast tile ----------------
// LDS word-granular; row-pairing via shfl_xor(32); run-rotation swizzle -> <=4-way write
// conflicts; reads ds_read_b128 + wave-uniform rotate. Needs 34816 B of LDS.
__device__ __forceinline__ void transpose_tile(const float* __restrict__ in,
                                               unsigned short* __restrict__ out,
                                               int R, int C, int c0, int r0,
                                               unsigned int* tileT32) {
    int tid = threadIdx.x;
    int l15 = tid & 15;
    int g = tid >> 4;
    int par = (g >> 1) & 1;        // parity of this thread's input row
    int hf = g & 1;
    int cb = hf * 64 + l15 * 4;
    #pragma unroll
    for (int p = 0; p < 16; p++) {
        int unit = p * 16 + g;
        int r = unit >> 1;
        float4 v = *(const float4*)(in + (size_t)(r0 + r) * C + c0 + cb);
        unsigned int m01 = (unsigned int)f2bf(v.x) | ((unsigned int)f2bf(v.y) << 16);
        unsigned int m23 = (unsigned int)f2bf(v.z) | ((unsigned int)f2bf(v.w) << 16);
        unsigned int o01 = __shfl_xor(m01, 32);   // partner (lane^32) holds row r^1, same cols
        unsigned int o23 = __shfl_xor(m23, 32);
        unsigned int wA = par ? ((o23 & 0xffffu) | (m23 << 16))
                              : ((m01 & 0xffffu) | (o01 << 16));
        unsigned int wB = par ? ((o23 >> 16) | (m23 & 0xffff0000u))
                              : ((m01 >> 16) | (o01 & 0xffff0000u));
        int ca = cb + par * 2;
        int rp = unit >> 2;                       // pair index r>>1
        int cq = ca >> 2;                         // same for ca and ca+1
        int woff = 4 * (((rp >> 2) + 3 * cq) & 15) + (((rp & 3) + cq) & 3);
        tileT32[ca * 68 + woff] = wA;
        tileT32[(ca + 1) * 68 + woff] = wB;
    }
    __syncthreads();
    #pragma unroll
    for (int p = 0; p < 8; p++) {
        int cc = p * 16 + g;                      // output row (= input col)
        int cqp = cc >> 2;                        // wave-uniform
        const uint4 W = *(const uint4*)&tileT32[cc * 68 + 4 * ((l15 + 3 * cqp) & 15)];
        unsigned int a0 = W.x, a1 = W.y, a2 = W.z, a3 = W.w;
        int rsel = cqp & 3;                       // wave-uniform rotate to undo k-scramble
        if (rsel & 1) { unsigned int t = a0; a0 = a1; a1 = a2; a2 = a3; a3 = t; }
        if (rsel & 2) { unsigned int t0 = a0, t1 = a1; a0 = a2; a1 = a3; a2 = t0; a3 = t1; }
        uint4 ov; ov.x = a0; ov.y = a1; ov.z = a2; ov.w = a3;
        *(uint4*)(out + (size_t)(c0 + cc) * R + r0 + l15 * 8) = ov;   // rows l15*8..+8 in order
    }
}

// ---------------- kernel 1: ALL transposes || cast_x || router ----------------
// blocks [0,1296):    transpose W1[e]/Ws1 (768x3072 -> [3072][768])
// blocks [1296,2592): transpose W2[e]/Ws2 (3072x768 -> [768][3072])
// blocks [2592,3360): cast x -> bf16
// blocks [3360,3872): router (one wave per token)
__global__ __launch_bounds__(256)
void pre_kernel(const float* __restrict__ x, const float* __restrict__ noise,
                const float* __restrict__ Wr, const float* __restrict__ br,
                const float* __restrict__ W1, const float* __restrict__ Ws1,
                const float* __restrict__ W2, const float* __restrict__ Ws2,
                unsigned short* __restrict__ W1t, unsigned short* __restrict__ Ws1t,
                unsigned short* __restrict__ W2t, unsigned short* __restrict__ Ws2t,
                unsigned short* __restrict__ xb,
                int* __restrict__ counts, int* __restrict__ list,
                int* __restrict__ inv, float* __restrict__ tokp) {
    __shared__ __align__(16) unsigned int tileT32[128 * 68];   // 34816 B
    int b = blockIdx.x;
    if (b < 1296) {
        int m = b / 144, t = b % 144;   // 9 matrices (W1[0..7], Ws1)
        const float* in       = (m < 8) ? (W1 + (size_t)m * DDIM * HDIM) : Ws1;
        unsigned short* out   = (m < 8) ? (W1t + (size_t)m * HDIM * DDIM) : Ws1t;
        transpose_tile(in, out, DDIM, HDIM, (t % 24) * 128, (t / 24) * 128, tileT32);
        return;
    }
    if (b < 2592) {
        int q = b - 1296;
        int m = q / 144, t = q % 144;   // 9 matrices (W2[0..7], Ws2)
        const float* in     = (m < 8) ? (W2 + (size_t)m * HDIM * DDIM) : Ws2;
        unsigned short* out = (m < 8) ? (W2t + (size_t)m * DDIM * HDIM) : Ws2t;
        transpose_tile(in, out, HDIM, DDIM, (t % 6) * 128, (t / 6) * 128, tileT32);
        return;
    }
    if (b < 3360) {
        int i = ((b - 2592) * 256 + threadIdx.x) * 8;
        float4 a = *(const float4*)(x + i);
        float4 bb = *(const float4*)(x + i + 4);
        ushort4 lo = make_ushort4(f2bf(a.x), f2bf(a.y), f2bf(a.z), f2bf(a.w));
        ushort4 hi = make_ushort4(f2bf(bb.x), f2bf(bb.y), f2bf(bb.z), f2bf(bb.w));
        *(ushort4*)(xb + i) = lo;
        *(ushort4*)(xb + i + 4) = hi;
        return;
    }
    // ---- router ----
    int lane = threadIdx.x & 63;
    int t = (b - 3360) * 4 + (threadIdx.x >> 6);
    float acc[8];
    #pragma unroll
    for (int e = 0; e < 8; e++) acc[e] = 0.f;
    #pragma unroll
    for (int i = 0; i < 12; i++) {
        int d = i * 64 + lane;
        float xv = x[t * DDIM + d];
        float4 w0 = *(const float4*)(Wr + d * 8);
        float4 w1 = *(const float4*)(Wr + d * 8 + 4);
        acc[0] += xv * w0.x; acc[1] += xv * w0.y; acc[2] += xv * w0.z; acc[3] += xv * w0.w;
        acc[4] += xv * w1.x; acc[5] += xv * w1.y; acc[6] += xv * w1.z; acc[7] += xv * w1.w;
    }
    #pragma unroll
    for (int e = 0; e < 8; e++) {
        #pragma unroll
        for (int off2 = 32; off2 >= 1; off2 >>= 1)
            acc[e] += __shfl_xor(acc[e], off2, 64);
    }
    if (lane == 0) {
        float lg[8];
        #pragma unroll
        for (int e = 0; e < 8; e++) lg[e] = acc[e] + br[e] + 0.1f * noise[t * 8 + e];
        int e0 = 0;
        #pragma unroll
        for (int e = 1; e < 8; e++) if (lg[e] > lg[e0]) e0 = e;
        int e1 = -1;
        #pragma unroll
        for (int e = 0; e < 8; e++) if (e != e0 && (e1 < 0 || lg[e] > lg[e1])) e1 = e;
        float m = fmaxf(lg[e0], lg[e1]);
        float p0 = expf(lg[e0] - m), p1 = expf(lg[e1] - m);
        float inv_s = 1.f / (p0 + p1);
        int s0 = atomicAdd(&counts[e0], 1);
        list[e0 * TNUM + s0] = t;
        int s1 = atomicAdd(&counts[e1], 1);
        list[e1 * TNUM + s1] = t;
        inv[t * 2 + 0] = (e0 << 16) | s0;
        inv[t * 2 + 1] = (e1 << 16) | s1;
        tokp[t * 2 + 0] = p0 * inv_s;
        tokp[t * 2 + 1] = p1 * inv_s;
    }
}

// ================= FFN kernels =================
// 2-LDS-buffer counted-vmcnt pipeline (minimum LDS -> max resident blocks/CU;
// empirical law R0-R3: aggregate throughput ~ resident blocks, per-step time const).
// Step kt: WAITVM(L) [tile kt arrived, kt+1 in flight] -> barrier -> compute buf[kt&1]
//          -> barrier -> issue tile kt+2 into buf[kt&1].
// In-order vmcnt semantics make WAITVM(L) wait exactly for the oldest tile's L loads.

// ---------------- GEMM layer 1: h = leaky(x @ W1[e] + b1[e]) ----------------
// BM=128, BN=128, BK=32, LDS 32KB -> 5 blocks/CU. 24 jobs:
//   j<16: expert e=j>>1, n-half nh=j&1; j>=16: shared slab (512 rows) x nh
__global__ __launch_bounds__(256, 4)
void ffn1_kernel(const unsigned short* __restrict__ xb,
                 const unsigned short* __restrict__ W1t,   // [8][3072][768]
                 const unsigned short* __restrict__ Ws1t,  // [3072][768]
                 const float* __restrict__ b1, const float* __restrict__ bs1,
                 const int* __restrict__ counts, const int* __restrict__ list,
                 unsigned short* __restrict__ hbuf) {      // [6144][3072]
    __shared__ __align__(16) unsigned short As[2][512 * 8];   // 2 x 8KB
    __shared__ __align__(16) unsigned short Bs[2][512 * 8];   // 2 x 8KB (32KB total)

    int j = blockIdx.z * 8 + blockIdx.x;    // 0..23
    int y = blockIdx.y;                     // 0..47
    int mt0 = y / 12, ntl = y % 12;         // mt0 0..3, ntl 0..11

    int offv[8];
    { int s = 0;
      #pragma unroll
      for (int e = 0; e < 8; e++) { offv[e] = s; s += counts[e]; } }

    int cnt, hbase, n0, mbase, ntiles;
    const unsigned short* Bmat;
    const float* bias;
    const int* lst = nullptr;
    if (j < 16) {
        int e = j >> 1, nh = j & 1;
        cnt = counts[e];
        ntiles = (cnt + 127) >> 7;
        mbase = 0;
        hbase = offv[e];
        n0 = nh * 1536 + ntl * 128;
        Bmat = W1t + (size_t)e * HDIM * DDIM;
        bias = b1 + e * HDIM;
        lst = list + e * TNUM;
    } else {
        int q = j - 16;                     // 0..7
        int ms = q >> 1, nh = q & 1;
        mbase = ms * 512;
        ntiles = 4;
        cnt = 1 << 30;
        hbase = 2 * TNUM;
        n0 = nh * 1536 + ntl * 128;
        Bmat = Ws1t;
        bias = bs1;
    }
    if (mt0 >= ntiles) return;

    int tid = threadIdx.x;
    int w = tid >> 6, lane = tid & 63;
    int l15 = lane & 15, quad = lane >> 4;
    int wm = (w & 1) * 64, wn = (w >> 1) * 64;
    int rcA = (w & 1) * 4;
    int rcB = (w >> 1) * 4;
    const int KT = DDIM / 32;   // 24

    const unsigned short* gB[2];
    int ldsoff[2], rowl[2];
    #pragma unroll
    for (int r = 0; r < 2; r++) {
        int rc = r * 4 + w;
        rowl[r] = rc * 16 + l15;
        ldsoff[r] = rc * 512;
        gB[r] = Bmat + (size_t)(n0 + rowl[r]) * DDIM + quad * 8;
    }

    for (int mt = mt0; mt < ntiles; mt += 4) {
        int m0 = mbase + mt * 128;
        const unsigned short* gA[2];
        #pragma unroll
        for (int r = 0; r < 2; r++) {
            int row;
            if (lst) row = lst[min(m0 + rowl[r], cnt - 1)];
            else     row = m0 + rowl[r];
            gA[r] = xb + (size_t)row * DDIM + quad * 8;
        }

        f32x4 zero = {0.f, 0.f, 0.f, 0.f};
        f32x4 acc[4][4];
        #pragma unroll
        for (int i = 0; i < 4; i++)
            #pragma unroll
            for (int jj = 0; jj < 4; jj++) acc[i][jj] = zero;

        // prologue: tiles 0 and 1 (prev m-tile's trailing barrier protects buffers)
        #pragma unroll
        for (int t = 0; t < 2; t++)
            #pragma unroll
            for (int r = 0; r < 2; r++) {
                async_cp16(gA[r] + t * 32, &As[t][ldsoff[r]]);
                async_cp16(gB[r] + t * 32, &Bs[t][ldsoff[r]]);
            }

        #pragma unroll 1
        for (int kt = 0; kt < KT; kt++) {
            if (kt == KT - 1) { WAITVM(0); } else { WAITVM(4); }   // oldest tile arrived
            __builtin_amdgcn_s_barrier();
            MEMFENCE();
            int cur = kt & 1;
            bf16x8 af[4], bv[4];
            #pragma unroll
            for (int i = 0; i < 4; i++)
                af[i] = *(const bf16x8*)&As[cur][((rcA + i) * 64 + quad * 16 + l15) * 8];
            #pragma unroll
            for (int jj = 0; jj < 4; jj++)
                bv[jj] = *(const bf16x8*)&Bs[cur][((rcB + jj) * 64 + quad * 16 + l15) * 8];
            #pragma unroll
            for (int i = 0; i < 4; i++)
                #pragma unroll
                for (int jj = 0; jj < 4; jj++)
                    acc[i][jj] = __builtin_amdgcn_mfma_f32_16x16x32_bf16(af[i], bv[jj], acc[i][jj], 0, 0, 0);
            MEMFENCE();
            __builtin_amdgcn_s_barrier();      // all waves done reading buf[cur]
            MEMFENCE();
            if (kt + 2 < KT) {
                int ko = (kt + 2) * 32;
                #pragma unroll
                for (int r = 0; r < 2; r++) {
                    async_cp16(gA[r] + ko, &As[cur][ldsoff[r]]);
                    async_cp16(gB[r] + ko, &Bs[cur][ldsoff[r]]);
                }
            }
        }

        #pragma unroll
        for (int i = 0; i < 4; i++) {
            int rbase = m0 + wm + i * 16 + quad * 4;
            #pragma unroll
            for (int jj = 0; jj < 4; jj++) {
                int gc = n0 + wn + jj * 16 + l15;
                float bvl = bias[gc];
                #pragma unroll
                for (int r = 0; r < 4; r++) {
                    int gr = rbase + r;
                    if (gr < cnt) {
                        float v = acc[i][jj][r] + bvl;
                        v = v > 0.f ? v : 0.01f * v;
                        hbuf[(size_t)(hbase + gr) * HDIM + gc] = f2bf(v);
                    }
                }
            }
        }
    }
}

// ---------------- GEMM layer 2: ybuf[kh] = h @ W2[e] (fp32 stores) ----------------
// BM=64, BN=128, BK=32, LDS 24KB -> 6 blocks/CU. 24 jobs:
//   j<16: expert e=j>>1, kh=j&1; j>=16: shared (mh 0..3, kh)
__global__ __launch_bounds__(256, 4)
void ffn2_kernel(const unsigned short* __restrict__ hbuf,
                 const unsigned short* __restrict__ W2t,   // [8][768][3072]
                 const unsigned short* __restrict__ Ws2t,  // [768][3072]
                 const int* __restrict__ counts,
                 float* __restrict__ ybuf) {               // [2][6144][768]
    __shared__ __align__(16) unsigned short As[2][256 * 8];   // 2 x 4KB
    __shared__ __align__(16) unsigned short Bs[2][512 * 8];   // 2 x 8KB (24KB total)

    int j = blockIdx.z * 8 + blockIdx.x;    // 0..23
    int y = blockIdx.y;                     // 0..47
    int mt0 = y / 6, ntl = y % 6;           // mt0 0..7, ntl 0..5
    int n0 = ntl * 128;

    int offv[8];
    { int s = 0;
      #pragma unroll
      for (int e = 0; e < 8; e++) { offv[e] = s; s += counts[e]; } }

    int cnt, hbase, mbase, kh, ntiles;
    const unsigned short* Bmat;
    if (j < 16) {
        int e = j >> 1; kh = j & 1;
        cnt = counts[e];
        ntiles = (cnt + 63) >> 6;
        mbase = 0;
        hbase = offv[e];
        Bmat = W2t + (size_t)e * DDIM * HDIM;
    } else {
        int q = j - 16;
        int mh = q >> 1; kh = q & 1;
        mbase = mh * 512;
        ntiles = 8;
        cnt = 1 << 30;
        hbase = 2 * TNUM;
        Bmat = Ws2t;
    }
    if (mt0 >= ntiles) return;
    int kbase = kh * (HDIM / 2);

    int tid = threadIdx.x;
    int w = tid >> 6, lane = tid & 63;
    int l15 = lane & 15, quad = lane >> 4;
    int wm = (w & 1) * 32, wn = (w >> 1) * 64;
    int rcA = (w & 1) * 2;
    int rcB = (w >> 1) * 4;
    const int KT = (HDIM / 2) / 32;   // 48
    int rowl = w * 16 + l15;

    const unsigned short* gB[2];
    int ldsoffB[2];
    #pragma unroll
    for (int r = 0; r < 2; r++) {
        int rc = r * 4 + w;
        gB[r] = Bmat + (size_t)(n0 + rc * 16 + l15) * HDIM + kbase + quad * 8;
        ldsoffB[r] = rc * 512;
    }
    float* yb = ybuf + (size_t)kh * 6144 * DDIM;

    for (int mt = mt0; mt < ntiles; mt += 8) {
        int m0 = mbase + mt * 64;
        int ra = (j < 16) ? min(m0 + rowl, cnt - 1) : (m0 + rowl);
        const unsigned short* gA0 = hbuf + (size_t)(hbase + ra) * HDIM + kbase + quad * 8;

        f32x4 zero = {0.f, 0.f, 0.f, 0.f};
        f32x4 acc[2][4];
        #pragma unroll
        for (int i = 0; i < 2; i++)
            #pragma unroll
            for (int jj = 0; jj < 4; jj++) acc[i][jj] = zero;

        #pragma unroll
        for (int t = 0; t < 2; t++) {
            async_cp16(gA0 + t * 32, &As[t][w * 512]);
            #pragma unroll
            for (int r = 0; r < 2; r++) async_cp16(gB[r] + t * 32, &Bs[t][ldsoffB[r]]);
        }

        #pragma unroll 1
        for (int kt = 0; kt < KT; kt++) {
            if (kt == KT - 1) { WAITVM(0); } else { WAITVM(3); }
            __builtin_amdgcn_s_barrier();
            MEMFENCE();
            int cur = kt & 1;
            bf16x8 af[2], bv[4];
            #pragma unroll
            for (int i = 0; i < 2; i++)
                af[i] = *(const bf16x8*)&As[cur][((rcA + i) * 64 + quad * 16 + l15) * 8];
            #pragma unroll
            for (int jj = 0; jj < 4; jj++)
                bv[jj] = *(const bf16x8*)&Bs[cur][((rcB + jj) * 64 + quad * 16 + l15) * 8];
            #pragma unroll
            for (int i = 0; i < 2; i++)
                #pragma unroll
                for (int jj = 0; jj < 4; jj++)
                    acc[i][jj] = __builtin_amdgcn_mfma_f32_16x16x32_bf16(af[i], bv[jj], acc[i][jj], 0, 0, 0);
            MEMFENCE();
            __builtin_amdgcn_s_barrier();      // all waves done reading buf[cur]
            MEMFENCE();
            if (kt + 2 < KT) {
                int ko = (kt + 2) * 32;
                async_cp16(gA0 + ko, &As[cur][w * 512]);
                #pragma unroll
                for (int r = 0; r < 2; r++) async_cp16(gB[r] + ko, &Bs[cur][ldsoffB[r]]);
            }
        }

        #pragma unroll
        for (int i = 0; i < 2; i++) {
            int rbase = m0 + wm + i * 16 + quad * 4;
            #pragma unroll
            for (int r = 0; r < 4; r++) {
                int gr = rbase + r;
                if (gr >= cnt) continue;
                float* orow = yb + (size_t)(hbase + gr) * DDIM + n0 + wn;
                #pragma unroll
                for (int jj = 0; jj < 4; jj++)
                    orow[jj * 16 + l15] = acc[i][jj][r];
            }
        }
    }
}

// ---------------- final mix (offs + softmax(alpha,beta) inline) ----------------
__global__ void mix_kernel(const float* __restrict__ ybuf, const int* __restrict__ inv,
                           const float* __restrict__ tokp, const int* __restrict__ counts,
                           const float* __restrict__ b2, const float* __restrict__ bs2,
                           const float* __restrict__ alpha, const float* __restrict__ beta,
                           float* __restrict__ out) {
    int t = blockIdx.x;
    int c = threadIdx.x * 4;          // blockDim = 192 -> covers 768
    int offv[8];
    { int s = 0;
      #pragma unroll
      for (int e = 0; e < 8; e++) { offv[e] = s; s += counts[e]; } }
    float a = alpha[0], bsc = beta[0];
    float m = fmaxf(a, bsc);
    float ea = expf(a - m), eb = expf(bsc - m);
    float is = 1.f / (ea + eb);
    float ws = ea * is, wmx = eb * is;

    int i0 = inv[t * 2 + 0], i1 = inv[t * 2 + 1];
    int e0 = i0 >> 16, sl0 = i0 & 0xFFFF;
    int e1 = i1 >> 16, sl1 = i1 & 0xFFFF;
    float p0 = tokp[t * 2 + 0], p1 = tokp[t * 2 + 1];
    size_t rA = (size_t)(offv[e0] + sl0) * DDIM + c;
    size_t rB = (size_t)(offv[e1] + sl1) * DDIM + c;
    size_t rS = (size_t)(2 * TNUM + t) * DDIM + c;
    const float* y0 = ybuf;
    const float* y1 = ybuf + (size_t)6144 * DDIM;
    float4 vA0 = *(const float4*)(y0 + rA);
    float4 vA1 = *(const float4*)(y1 + rA);
    float4 vB0 = *(const float4*)(y0 + rB);
    float4 vB1 = *(const float4*)(y1 + rB);
    float4 vS0 = *(const float4*)(y0 + rS);
    float4 vS1 = *(const float4*)(y1 + rS);
    float4 bA = *(const float4*)(b2 + e0 * DDIM + c);
    float4 bB = *(const float4*)(b2 + e1 * DDIM + c);
    float4 bS = *(const float4*)(bs2 + c);
    float4 o;
    o.x = ws * (vS0.x + vS1.x + bS.x) + wmx * (p0 * (vA0.x + vA1.x + bA.x) + p1 * (vB0.x + vB1.x + bB.x));
    o.y = ws * (vS0.y + vS1.y + bS.y) + wmx * (p0 * (vA0.y + vA1.y + bA.y) + p1 * (vB0.y + vB1.y + bB.y));
    o.z = ws * (vS0.z + vS1.z + bS.z) + wmx * (p0 * (vA0.z + vA1.z + bA.z) + p1 * (vB0.z + vB1.z + bB.z));
    o.w = ws * (vS0.w + vS1.w + bS.w) + wmx * (p0 * (vA0.w + vA1.w + bA.w) + p1 * (vB0.w + vB1.w + bB.w));
    *(float4*)(out + (size_t)t * DDIM + c) = o;
}

extern "C" void kernel_launch(void* const* d_in, const int* in_sizes, int n_in,
                              void* d_out, int out_size, void* d_ws, size_t ws_size,
                              hipStream_t stream) {
    const float* x     = (const float*)d_in[0];
    const float* noise = (const float*)d_in[1];
    const float* Wr    = (const float*)d_in[2];
    const float* br    = (const float*)d_in[3];
    const float* W1    = (const float*)d_in[4];
    const float* b1    = (const float*)d_in[5];
    const float* W2    = (const float*)d_in[6];
    const float* b2    = (const float*)d_in[7];
    const float* Ws1   = (const float*)d_in[8];
    const float* bs1   = (const float*)d_in[9];
    const float* Ws2   = (const float*)d_in[10];
    const float* bs2   = (const float*)d_in[11];
    const float* alpha = (const float*)d_in[12];
    const float* beta  = (const float*)d_in[13];

    char* ws = (char*)d_ws;
    size_t off = 0;
    auto alloc = [&](size_t bytes) -> char* {
        char* p = ws + off;
        off = (off + bytes + 255) & ~(size_t)255;
        return p;
    };
    int*   counts = (int*)  alloc(ENUM * 4);
    int*   list   = (int*)  alloc((size_t)ENUM * TNUM * 4);
    int*   inv    = (int*)  alloc((size_t)TNUM * 2 * 4);
    float* tokp   = (float*)alloc((size_t)TNUM * 2 * 4);
    unsigned short* xb   = (unsigned short*)alloc((size_t)TNUM * DDIM * 2);
    unsigned short* W1t  = (unsigned short*)alloc((size_t)ENUM * HDIM * DDIM * 2);  // 36 MB
    unsigned short* Ws1t = (unsigned short*)alloc((size_t)HDIM * DDIM * 2);         // 4.5 MB (adjacent)
    unsigned short* W2t  = (unsigned short*)alloc((size_t)ENUM * DDIM * HDIM * 2);
    unsigned short* Ws2t = (unsigned short*)alloc((size_t)DDIM * HDIM * 2);
    unsigned short* hbuf = (unsigned short*)alloc((size_t)(3 * TNUM) * HDIM * 2);
    // ybuf (2*6144*768*4 = 37.75 MB) aliases W1t+Ws1t (40.5 MB contiguous): last reader of
    // W1t/Ws1t is ffn1; ffn2 writes ybuf strictly after on the same stream.
    float* ybuf = (float*)W1t;
    if (off > ws_size) {
        fprintf(stderr, "kernel_launch: workspace too small (need %zu, have %zu)\n", off, ws_size);
        return;
    }

    hipMemsetAsync(counts, 0, ENUM * 4, stream);

    // k1: all transposes + cast + router (2592 + 768 + 512 blocks)
    pre_kernel<<<dim3(3872), dim3(256), 0, stream>>>(x, noise, Wr, br, W1, Ws1, W2, Ws2,
                                                     W1t, Ws1t, W2t, Ws2t, xb,
                                                     counts, list, inv, tokp);
    // k2: ffn1, 24 jobs, 32KB LDS
    ffn1_kernel<<<dim3(8, 48, 3), dim3(256), 0, stream>>>(xb, W1t, Ws1t, b1, bs1, counts, list, hbuf);
    // k3: ffn2, 24 jobs (kh split), 24KB LDS
    ffn2_kernel<<<dim3(8, 48, 3), dim3(256), 0, stream>>>(hbuf, W2t, Ws2t, counts, ybuf);
    // k4: mix
    mix_kernel<<<dim3(TNUM), dim3(192), 0, stream>>>(ybuf, inv, tokp, counts, b2, bs2,
                                                     alpha, beta, (float*)d_out);
}